// Round 9
// baseline (7153.767 us; speedup 1.0000x reference)
//
#include <hip/hip_runtime.h>
#include <hip/hip_bf16.h>

#define SEQ   2048
#define NBATCH 64
#define HID   512
#define KDIM  512

typedef float f32x4  __attribute__((ext_vector_type(4)));
typedef short bf16x8 __attribute__((ext_vector_type(8)));

__device__ __forceinline__ unsigned short f2bf(float f) {
  union { float f; unsigned int u; } v; v.f = f;
  unsigned int r = v.u + 0x7FFFu + ((v.u >> 16) & 1u);
  return (unsigned short)(r >> 16);
}

__device__ __forceinline__ f32x4 mfma16(bf16x8 a, bf16x8 b, f32x4 c) {
  return __builtin_amdgcn_mfma_f32_16x16x32_bf16(a, b, c, 0, 0, 0);
}

// Repack W [H=512 rows n][K=512 cols k] (row-major fp32) into MFMA-fragment-major bf16:
// element index = ((kf*32 + cfg)*64 + lane)*8 + e  with n = cfg*16 + (lane&15),
// k = kf*32 + (lane>>4)*8 + e.
__global__ void prep_wfrag(const float* __restrict__ W, unsigned short* __restrict__ dst) {
  int tid = blockIdx.x * blockDim.x + threadIdx.x;   // 0 .. 262143
  int e   = tid & 7;
  int l   = (tid >> 3) & 63;
  int cfg = (tid >> 9) & 31;
  int kf  = tid >> 14;
  int n = cfg * 16 + (l & 15);
  int k = kf * 32 + (l >> 4) * 8 + e;
  dst[tid] = f2bf(W[n * KDIM + k]);
}

__global__ void prep_bsum(const float* __restrict__ a, const float* __restrict__ b,
                          float* __restrict__ out) {
  int j = threadIdx.x;
  if (j < HID) out[j] = a[j] + b[j];
}

// Phase 1: xp = X * W_ih^T + (b_ih + b_hh), NATURAL layout [s*64+b][n] fp32.
__global__ __launch_bounds__(512) void rnn_xproj(
    const float* __restrict__ X,
    const uint4* __restrict__ BW,
    const float* __restrict__ bsum,
    float* __restrict__ out) {
  const int tid = threadIdx.x, w = tid >> 6, l = tid & 63;
  const int g = l >> 4, lr = l & 15;
  const int rowbase = blockIdx.x * 64 + (w >> 2) * 32;
  const int colw = (w & 3) * 128;

  f32x4 acc[2][8];
  #pragma unroll
  for (int cf = 0; cf < 8; ++cf) {
    float bv = bsum[colw + cf * 16 + lr];
    f32x4 z = {bv, bv, bv, bv};
    acc[0][cf] = z; acc[1][cf] = z;
  }

  #pragma unroll 1
  for (int kc = 0; kc < 16; ++kc) {
    const int kb = kc * 32 + g * 8;
    bf16x8 afr[2];
    #pragma unroll
    for (int ai = 0; ai < 2; ++ai) {
      const float* src = X + (size_t)(rowbase + ai * 16 + lr) * KDIM + kb;
      float4 lo = *reinterpret_cast<const float4*>(src);
      float4 hi = *reinterpret_cast<const float4*>(src + 4);
      bf16x8 a;
      a[0] = (short)f2bf(lo.x); a[1] = (short)f2bf(lo.y);
      a[2] = (short)f2bf(lo.z); a[3] = (short)f2bf(lo.w);
      a[4] = (short)f2bf(hi.x); a[5] = (short)f2bf(hi.y);
      a[6] = (short)f2bf(hi.z); a[7] = (short)f2bf(hi.w);
      afr[ai] = a;
    }
    #pragma unroll
    for (int cf = 0; cf < 8; ++cf) {
      const int cfg = (w & 3) * 8 + cf;
      uint4 braw = BW[(kc * 32 + cfg) * 64 + l];
      bf16x8 b = __builtin_bit_cast(bf16x8, braw);
      acc[0][cf] = mfma16(afr[0], b, acc[0][cf]);
      acc[1][cf] = mfma16(afr[1], b, acc[1][cf]);
    }
  }

  #pragma unroll
  for (int ai = 0; ai < 2; ++ai) {
    #pragma unroll
    for (int cf = 0; cf < 8; ++cf) {
      const int col = colw + cf * 16 + lr;
      #pragma unroll
      for (int r = 0; r < 4; ++r) {
        const int row = rowbase + ai * 16 + g * 4 + r;
        out[(size_t)row * HID + col] = acc[ai][cf][r];
      }
    }
  }
}

// Phase 2: barrier-FREE sequential scan (producer/consumer flags).
// 4 blocks x 512 threads (8 waves, 2/SIMD). Wave w owns mf = w*4..w*4+3,
// i.e. n in [w*64,(w+1)*64) = h frags 2w, 2w+1 (sole producer of those frags).
// LDS (163840 B):
//   [0,130048):      W_hh A-frags kf0-3, frags 0..126 (frag f at f*1024)
//   [130048,130080): prod[8]   (step counter: wave w wrote its h frags for step t)
//   [130080,130112): rdcnt[8]  (step counter: wave w done READING h(t-1))
//   [130112,131072): unused (stale staging bytes)
//   [131072,147456): h buf0 (frag layout: frag kf at kf*1024, elem (l,e) at l*16+e*2)
//   [147456,163840): h buf1
// Frag 127 (kf3,mf31) lives in wave-7 registers (ar33). W_hh kf4..15 in 192 regs.
// Protocol per step t: spin prod[0..3]>=t-1 before kf0; spin prod[4..7]>=t-1
// before kf8; after last hb read post rdcnt[w]=t; gate rdcnt[*]>=t-1 before
// h(t) writes (overwrite of h(t-2)); post prod[w]=t after writes.
// Spins are BOUNDED (2048 sleeps ~ 100x any legit wait): a protocol bug
// terminates with a wrong answer instead of a GPU hang.
#define PRODOFF 130048
#define RDCOFF  130080

__global__ __launch_bounds__(512, 2) void rnn_scan(
    const uint4* __restrict__ BW,   // W_hh frag-major bf16 (16384 frags)
    float* __restrict__ xo) {       // d_out: xp in (natural), h out (natural)
  extern __shared__ char smem[];
  const int tid = threadIdx.x, w = tid >> 6, l = tid & 63;
  const int g = l >> 4, lr = l & 15;
  const int bg = blockIdx.x;

  // stage W_hh kf0-3 (128 KB, linear) — NOTE: overwrites the flag region bytes
  {
    uint4* lb = reinterpret_cast<uint4*>(smem);
    #pragma unroll
    for (int i = 0; i < 16; ++i) lb[i * 512 + tid] = BW[i * 512 + tid];
  }
  // zero h buf1 (read by step 0)
  {
    float* hz = reinterpret_cast<float*>(smem + 147456);
    #pragma unroll
    for (int i = 0; i < 8; ++i) hz[i * 512 + tid] = 0.f;
  }
  // register A-frags kf4..15 (static indices) + wave-7's carved frag 127
  bf16x8 ar[12][4];
  #pragma unroll
  for (int kf = 0; kf < 12; ++kf)
    #pragma unroll
    for (int mf = 0; mf < 4; ++mf)
      ar[kf][mf] = __builtin_bit_cast(bf16x8,
          BW[((kf + 4) * 32 + (w * 4 + mf)) * 64 + l]);
  bf16x8 ar33 = __builtin_bit_cast(bf16x8, BW[127 * 64 + l]);

  // RACE FIX (r8 hang): staging writes [0,131072) INCLUDING the flag bytes.
  // Must complete block-wide before flags are initialized.
  __syncthreads();
  if (tid < 16) ((volatile int*)(smem + PRODOFF))[tid] = -1;
  __syncthreads();

  // startup stagger: ~256*w cycles (protocol caps skew at ~1 step anyway)
  for (int i = 0; i < w; ++i) __builtin_amdgcn_s_sleep(4);

  // per-lane constants
  const int hoff = l * 16;                        // hb read offset within frag
  const int apre = (w * 4) * 1024 + l * 16;       // + kf*32768 + mf*1024
  const int hwb  = (w * 2) * 1024 + (g >> 1) * 256 + (g & 1) * 8 + lr * 16;
  float* xrow0 = xo + ((size_t)bg * 16 + lr) * HID + (size_t)(w * 4) * 16 + g * 4;

#define HB(kf, RD) (*reinterpret_cast<const bf16x8*>(                            \
    smem + 131072 + (RD) + (kf) * 1024 + hoff))
#define SPIN(OFF, MASK, T)                                                       \
  {                                                                              \
    const volatile int* pf = (const volatile int*)(smem + (OFF) + ((l & (MASK)) << 2)); \
    int _gd = 0;                                                                 \
    while (__ballot(*pf < (T)) && _gd < 2048) {                                  \
      __builtin_amdgcn_s_sleep(1); ++_gd;                                        \
    }                                                                            \
    __builtin_amdgcn_sched_barrier(0);                                           \
  }

#define SCAN_STEP(S, RD, WR)                                                     \
  {                                                                              \
    const int s = (S);                                                           \
    f32x4 acc[4];                                                                \
    _Pragma("unroll")                                                            \
    for (int mf = 0; mf < 4; ++mf) { f32x4 z = {0.f,0.f,0.f,0.f}; acc[mf] = z; } \
    /* wait: frags 0..7 (producers 0..3) ready for step s-1 */                   \
    SPIN(PRODOFF, 3, s - 1)                                                      \
    /* kf0-2: LDS A */                                                           \
    _Pragma("unroll")                                                            \
    for (int kf = 0; kf < 3; ++kf) {                                             \
      bf16x8 hb = HB(kf, RD);                                                    \
      const char* ab = smem + kf * 32768 + apre;                                 \
      acc[0] = mfma16(*reinterpret_cast<const bf16x8*>(ab       ), hb, acc[0]);  \
      acc[1] = mfma16(*reinterpret_cast<const bf16x8*>(ab + 1024), hb, acc[1]);  \
      acc[2] = mfma16(*reinterpret_cast<const bf16x8*>(ab + 2048), hb, acc[2]);  \
      acc[3] = mfma16(*reinterpret_cast<const bf16x8*>(ab + 3072), hb, acc[3]);  \
    }                                                                            \
    /* kf3: LDS A, except wave 7's mf3 = carved frag 127 from regs */            \
    {                                                                            \
      bf16x8 hb = HB(3, RD);                                                     \
      const char* ab = smem + 3 * 32768 + apre;                                  \
      bf16x8 a3 = (w == 7) ? ar33                                                \
                           : *reinterpret_cast<const bf16x8*>(ab + 3072);        \
      acc[0] = mfma16(*reinterpret_cast<const bf16x8*>(ab       ), hb, acc[0]);  \
      acc[1] = mfma16(*reinterpret_cast<const bf16x8*>(ab + 1024), hb, acc[1]);  \
      acc[2] = mfma16(*reinterpret_cast<const bf16x8*>(ab + 2048), hb, acc[2]);  \
      acc[3] = mfma16(a3, hb, acc[3]);                                           \
    }                                                                            \
    /* xp(s) loads: used in epilogue ~1500+ cyc later */                         \
    const float* xrs = xrow0 + (size_t)s * (64 * HID);                           \
    f32x4 xt0 = *reinterpret_cast<const f32x4*>(xrs);                            \
    f32x4 xt1 = *reinterpret_cast<const f32x4*>(xrs + 16);                       \
    f32x4 xt2 = *reinterpret_cast<const f32x4*>(xrs + 32);                       \
    f32x4 xt3 = *reinterpret_cast<const f32x4*>(xrs + 48);                       \
    /* wait: frags 8..15 (producers 4..7) ready for step s-1 */                  \
    SPIN(PRODOFF + 16, 3, s - 1)                                                 \
    /* kf4-15: reg A */                                                          \
    _Pragma("unroll")                                                            \
    for (int kf = 0; kf < 12; ++kf) {                                            \
      bf16x8 hb = HB(kf + 4, RD);                                                \
      acc[0] = mfma16(ar[kf][0], hb, acc[0]);                                    \
      acc[1] = mfma16(ar[kf][1], hb, acc[1]);                                    \
      acc[2] = mfma16(ar[kf][2], hb, acc[2]);                                    \
      acc[3] = mfma16(ar[kf][3], hb, acc[3]);                                    \
    }                                                                            \
    /* all h(s-1) reads returned -> post rdcnt */                                \
    asm volatile("s_waitcnt lgkmcnt(0)" ::: "memory");                           \
    if (l == 0) *(volatile int*)(smem + RDCOFF + (w << 2)) = s;                  \
    /* epilogue: tanh + global stores (no gate needed for these) */              \
    float* orow = xrow0 + (size_t)s * (64 * HID);                                \
    f32x4 hv0, hv1, hv2, hv3;                                                    \
    _Pragma("unroll")                                                            \
    for (int r = 0; r < 4; ++r) {                                                \
      hv0[r] = 1.0f - 2.0f * __builtin_amdgcn_rcpf(1.0f + __expf(2.0f * (acc[0][r] + xt0[r]))); \
      hv1[r] = 1.0f - 2.0f * __builtin_amdgcn_rcpf(1.0f + __expf(2.0f * (acc[1][r] + xt1[r]))); \
      hv2[r] = 1.0f - 2.0f * __builtin_amdgcn_rcpf(1.0f + __expf(2.0f * (acc[2][r] + xt2[r]))); \
      hv3[r] = 1.0f - 2.0f * __builtin_amdgcn_rcpf(1.0f + __expf(2.0f * (acc[3][r] + xt3[r]))); \
    }                                                                            \
    *reinterpret_cast<f32x4*>(orow)      = hv0;                                  \
    *reinterpret_cast<f32x4*>(orow + 16) = hv1;                                  \
    *reinterpret_cast<f32x4*>(orow + 32) = hv2;                                  \
    *reinterpret_cast<f32x4*>(orow + 48) = hv3;                                  \
    /* gate: all waves done reading h(s-2) before overwriting its buffer */      \
    SPIN(RDCOFF, 7, s - 1)                                                       \
    uint2 hp;                                                                    \
    hp.x = (unsigned)f2bf(hv0[0]) | ((unsigned)f2bf(hv0[1]) << 16);              \
    hp.y = (unsigned)f2bf(hv0[2]) | ((unsigned)f2bf(hv0[3]) << 16);              \
    *reinterpret_cast<uint2*>(smem + 131072 + (WR) + hwb)        = hp;           \
    hp.x = (unsigned)f2bf(hv1[0]) | ((unsigned)f2bf(hv1[1]) << 16);              \
    hp.y = (unsigned)f2bf(hv1[2]) | ((unsigned)f2bf(hv1[3]) << 16);              \
    *reinterpret_cast<uint2*>(smem + 131072 + (WR) + hwb + 512)  = hp;           \
    hp.x = (unsigned)f2bf(hv2[0]) | ((unsigned)f2bf(hv2[1]) << 16);              \
    hp.y = (unsigned)f2bf(hv2[2]) | ((unsigned)f2bf(hv2[3]) << 16);              \
    *reinterpret_cast<uint2*>(smem + 131072 + (WR) + hwb + 1024) = hp;           \
    hp.x = (unsigned)f2bf(hv3[0]) | ((unsigned)f2bf(hv3[1]) << 16);              \
    hp.y = (unsigned)f2bf(hv3[2]) | ((unsigned)f2bf(hv3[3]) << 16);              \
    *reinterpret_cast<uint2*>(smem + 131072 + (WR) + hwb + 1536) = hp;           \
    /* h(s) data visible before flag */                                          \
    asm volatile("s_waitcnt lgkmcnt(0)" ::: "memory");                           \
    if (l == 0) *(volatile int*)(smem + PRODOFF + (w << 2)) = s;                 \
  }

  #pragma unroll 1
  for (int s2 = 0; s2 < SEQ; s2 += 2) {
    SCAN_STEP(s2,     16384, 0)      // even step: read buf1 (h(s-1)), write buf0
    SCAN_STEP(s2 + 1, 0,     16384)  // odd step:  read buf0,          write buf1
  }
#undef SCAN_STEP
#undef SPIN
#undef HB
}

extern "C" void kernel_launch(void* const* d_in, const int* in_sizes, int n_in,
                              void* d_out, int out_size, void* d_ws, size_t ws_size,
                              hipStream_t stream) {
  (void)in_sizes; (void)n_in; (void)out_size;
  const float* X   = (const float*)d_in[0];
  const float* Wih = (const float*)d_in[1];
  const float* Whh = (const float*)d_in[2];
  const float* bih = (const float*)d_in[3];
  const float* bhh = (const float*)d_in[4];
  float* out = (float*)d_out;

  unsigned short* wihf = (unsigned short*)d_ws;              // 512 KB
  unsigned short* whhf = wihf + 262144;                      // 512 KB
  float* bsum = (float*)(whhf + 262144);                     // 2 KB
  if (ws_size < (size_t)(2 * 524288 + 2048)) return;

  prep_wfrag<<<1024, 256, 0, stream>>>(Wih, wihf);
  prep_wfrag<<<1024, 256, 0, stream>>>(Whh, whhf);
  prep_bsum<<<1, 512, 0, stream>>>(bih, bhh, bsum);

  rnn_xproj<<<2048, 512, 0, stream>>>(X, (const uint4*)wihf, bsum, out);

  hipFuncSetAttribute(reinterpret_cast<const void*>(rnn_scan),
                      hipFuncAttributeMaxDynamicSharedMemorySize, 163840);
  rnn_scan<<<4, 512, 163840, stream>>>((const uint4*)whhf, out);
}

// Round 10
// 5028.154 us; speedup vs baseline: 1.4227x; 1.4227x over previous
//
#include <hip/hip_runtime.h>
#include <hip/hip_bf16.h>

#define SEQ   2048
#define NBATCH 64
#define HID   512
#define KDIM  512

typedef float f32x4  __attribute__((ext_vector_type(4)));
typedef short bf16x8 __attribute__((ext_vector_type(8)));

__device__ __forceinline__ unsigned short f2bf(float f) {
  union { float f; unsigned int u; } v; v.f = f;
  unsigned int r = v.u + 0x7FFFu + ((v.u >> 16) & 1u);
  return (unsigned short)(r >> 16);
}

__device__ __forceinline__ f32x4 mfma16(bf16x8 a, bf16x8 b, f32x4 c) {
  return __builtin_amdgcn_mfma_f32_16x16x32_bf16(a, b, c, 0, 0, 0);
}

// Repack W [H=512 rows n][K=512 cols k] (row-major fp32) into MFMA-fragment-major bf16:
// element index = ((kf*32 + cfg)*64 + lane)*8 + e  with n = cfg*16 + (lane&15),
// k = kf*32 + (lane>>4)*8 + e.
__global__ void prep_wfrag(const float* __restrict__ W, unsigned short* __restrict__ dst) {
  int tid = blockIdx.x * blockDim.x + threadIdx.x;   // 0 .. 262143
  int e   = tid & 7;
  int l   = (tid >> 3) & 63;
  int cfg = (tid >> 9) & 31;
  int kf  = tid >> 14;
  int n = cfg * 16 + (l & 15);
  int k = kf * 32 + (l >> 4) * 8 + e;
  dst[tid] = f2bf(W[n * KDIM + k]);
}

__global__ void prep_bsum(const float* __restrict__ a, const float* __restrict__ b,
                          float* __restrict__ out) {
  int j = threadIdx.x;
  if (j < HID) out[j] = a[j] + b[j];
}

// Phase 1: xp = X * W_ih^T + (b_ih + b_hh), NATURAL layout [s*64+b][n] fp32.
__global__ __launch_bounds__(512) void rnn_xproj(
    const float* __restrict__ X,
    const uint4* __restrict__ BW,
    const float* __restrict__ bsum,
    float* __restrict__ out) {
  const int tid = threadIdx.x, w = tid >> 6, l = tid & 63;
  const int g = l >> 4, lr = l & 15;
  const int rowbase = blockIdx.x * 64 + (w >> 2) * 32;
  const int colw = (w & 3) * 128;

  f32x4 acc[2][8];
  #pragma unroll
  for (int cf = 0; cf < 8; ++cf) {
    float bv = bsum[colw + cf * 16 + lr];
    f32x4 z = {bv, bv, bv, bv};
    acc[0][cf] = z; acc[1][cf] = z;
  }

  #pragma unroll 1
  for (int kc = 0; kc < 16; ++kc) {
    const int kb = kc * 32 + g * 8;
    bf16x8 afr[2];
    #pragma unroll
    for (int ai = 0; ai < 2; ++ai) {
      const float* src = X + (size_t)(rowbase + ai * 16 + lr) * KDIM + kb;
      float4 lo = *reinterpret_cast<const float4*>(src);
      float4 hi = *reinterpret_cast<const float4*>(src + 4);
      bf16x8 a;
      a[0] = (short)f2bf(lo.x); a[1] = (short)f2bf(lo.y);
      a[2] = (short)f2bf(lo.z); a[3] = (short)f2bf(lo.w);
      a[4] = (short)f2bf(hi.x); a[5] = (short)f2bf(hi.y);
      a[6] = (short)f2bf(hi.z); a[7] = (short)f2bf(hi.w);
      afr[ai] = a;
    }
    #pragma unroll
    for (int cf = 0; cf < 8; ++cf) {
      const int cfg = (w & 3) * 8 + cf;
      uint4 braw = BW[(kc * 32 + cfg) * 64 + l];
      bf16x8 b = __builtin_bit_cast(bf16x8, braw);
      acc[0][cf] = mfma16(afr[0], b, acc[0][cf]);
      acc[1][cf] = mfma16(afr[1], b, acc[1][cf]);
    }
  }

  #pragma unroll
  for (int ai = 0; ai < 2; ++ai) {
    #pragma unroll
    for (int cf = 0; cf < 8; ++cf) {
      const int col = colw + cf * 16 + lr;
      #pragma unroll
      for (int r = 0; r < 4; ++r) {
        const int row = rowbase + ai * 16 + g * 4 + r;
        out[(size_t)row * HID + col] = acc[ai][cf][r];
      }
    }
  }
}

// Phase 2: sequential scan, orientation-swapped: D[n_out][b] = sum_k W[n_out][k] h[b][k].
// 4 blocks x 512 threads (8 waves, 2/SIMD). Wave w owns mf = w*4..w*4+3.
// LDS (163840 B):
//   [0,131072):      W_hh A-frags kf0-3 (linear, frag f=kf*32+mf_g at f*1024)
//   [131072,147456): h buf0 in B-FRAGMENT layout: frag kf at kf*1024,
//                    elem (lane l, e) at l*16+e*2 = h[b=l&15][kf*32+(l>>4)*8+e]
//   [147456,163840): h buf1
// -> hb reads AND A reads are linear ds_read_b128 (conflict-free);
//    h writes are uint2 pairs (2-way, free).  W_hh kf4..15 in 192 regs.
// Per-step fixes vs r5: (1) frag-layout h kills the 5.2M bank conflicts;
// (2) kf0's A-quad is prefetched during the PREVIOUS step's epilogue/barrier
//     drain (static W -> no hazard), shrinking the post-barrier LDS burst;
// (3) single fused lgkmcnt(0)+s_barrier, no sched pinning, no setprio.
__global__ __launch_bounds__(512, 2) void rnn_scan(
    const uint4* __restrict__ BW,   // W_hh frag-major bf16 (16384 frags)
    float* __restrict__ xo) {       // d_out: xp in (natural), h out (natural)
  extern __shared__ char smem[];
  const int tid = threadIdx.x, w = tid >> 6, l = tid & 63;
  const int g = l >> 4, lr = l & 15;
  const int bg = blockIdx.x;

  // stage W_hh kf0-3 (128 KB, linear)
  {
    uint4* lb = reinterpret_cast<uint4*>(smem);
    #pragma unroll
    for (int i = 0; i < 16; ++i) lb[i * 512 + tid] = BW[i * 512 + tid];
  }
  // zero h buf1 (step 0 reads RD=16384; zeros valid in any layout)
  {
    float* hz = reinterpret_cast<float*>(smem + 147456);
    #pragma unroll
    for (int i = 0; i < 8; ++i) hz[i * 512 + tid] = 0.f;
  }
  // register A-frags kf4..15 for this wave's 4 m-frags (static indices only)
  bf16x8 ar[12][4];
  #pragma unroll
  for (int kf = 0; kf < 12; ++kf)
    #pragma unroll
    for (int mf = 0; mf < 4; ++mf)
      ar[kf][mf] = __builtin_bit_cast(bf16x8,
          BW[((kf + 4) * 32 + (w * 4 + mf)) * 64 + l]);
  __syncthreads();

  // per-lane constants
  const int hoff = l * 16;                        // hb read offset within frag
  const int apre = (w * 4) * 1024 + l * 16;       // + kf*32768 + mf*1024
  const int hwb  = (w * 2) * 1024 + (g >> 1) * 256 + (g & 1) * 8 + lr * 16;
  float* xrow0 = xo + ((size_t)bg * 16 + lr) * HID + (size_t)(w * 4) * 16 + g * 4;

#define HB(kf, RD) (*reinterpret_cast<const bf16x8*>(                            \
    smem + 131072 + (RD) + (kf) * 1024 + hoff))
#define AF(kf, mf) (*reinterpret_cast<const bf16x8*>(                            \
    smem + (kf) * 32768 + apre + (mf) * 1024))

  // prologue: xp(0) -> regs; kf0 A-quad -> regs
  f32x4 xv[4];
  #pragma unroll
  for (int mf = 0; mf < 4; ++mf)
    xv[mf] = *reinterpret_cast<const f32x4*>(xrow0 + mf * 16);
  bf16x8 pa0 = AF(0, 0), pa1 = AF(0, 1), pa2 = AF(0, 2), pa3 = AF(0, 3);

#define SCAN_STEP(S, RD, WR)                                                      \
  {                                                                               \
    const int s = (S);                                                            \
    f32x4 acc[4];                                                                 \
    _Pragma("unroll")                                                             \
    for (int mf = 0; mf < 4; ++mf) acc[mf] = xv[mf];                              \
    { /* prefetch xp(s+1) (consumed next step; clamp harmless at tail) */         \
      const float* xn = xrow0 + (size_t)(s + 1 < SEQ ? s + 1 : s) * (64 * HID);   \
      _Pragma("unroll")                                                           \
      for (int mf = 0; mf < 4; ++mf)                                              \
        xv[mf] = *reinterpret_cast<const f32x4*>(xn + mf * 16);                   \
    }                                                                             \
    /* kf0: A prefetched last step (pa0-3), only the hb read hits LDS */          \
    {                                                                             \
      bf16x8 hb = HB(0, RD);                                                      \
      acc[0] = mfma16(pa0, hb, acc[0]);                                           \
      acc[1] = mfma16(pa1, hb, acc[1]);                                           \
      acc[2] = mfma16(pa2, hb, acc[2]);                                           \
      acc[3] = mfma16(pa3, hb, acc[3]);                                           \
    }                                                                             \
    /* kf1-3: LDS A */                                                            \
    _Pragma("unroll")                                                             \
    for (int kf = 1; kf < 4; ++kf) {                                              \
      bf16x8 hb = HB(kf, RD);                                                     \
      const char* ab = smem + kf * 32768 + apre;                                  \
      acc[0] = mfma16(*reinterpret_cast<const bf16x8*>(ab       ), hb, acc[0]);   \
      acc[1] = mfma16(*reinterpret_cast<const bf16x8*>(ab + 1024), hb, acc[1]);   \
      acc[2] = mfma16(*reinterpret_cast<const bf16x8*>(ab + 2048), hb, acc[2]);   \
      acc[3] = mfma16(*reinterpret_cast<const bf16x8*>(ab + 3072), hb, acc[3]);   \
    }                                                                             \
    /* kf4-15: reg A */                                                           \
    _Pragma("unroll")                                                             \
    for (int kf = 0; kf < 12; ++kf) {                                             \
      bf16x8 hb = HB(kf + 4, RD);                                                 \
      acc[0] = mfma16(ar[kf][0], hb, acc[0]);                                     \
      acc[1] = mfma16(ar[kf][1], hb, acc[1]);                                     \
      acc[2] = mfma16(ar[kf][2], hb, acc[2]);                                     \
      acc[3] = mfma16(ar[kf][3], hb, acc[3]);                                     \
    }                                                                             \
    /* epilogue: tanh, f32x4 out, frag-layout h write (uint2, 2-way free) */      \
    float* orow = xrow0 + (size_t)s * (64 * HID);                                 \
    _Pragma("unroll")                                                             \
    for (int mf = 0; mf < 4; ++mf) {                                              \
      f32x4 hv;                                                                   \
      _Pragma("unroll")                                                           \
      for (int r = 0; r < 4; ++r) {                                               \
        const float pre = acc[mf][r];                                             \
        hv[r] = 1.0f - 2.0f * __builtin_amdgcn_rcpf(1.0f + __expf(2.0f * pre));   \
      }                                                                           \
      *reinterpret_cast<f32x4*>(orow + mf * 16) = hv;                             \
      uint2 hp;                                                                   \
      hp.x = (unsigned)f2bf(hv[0]) | ((unsigned)f2bf(hv[1]) << 16);               \
      hp.y = (unsigned)f2bf(hv[2]) | ((unsigned)f2bf(hv[3]) << 16);               \
      *reinterpret_cast<uint2*>(smem + 131072 + (WR) + hwb +                      \
          (mf >> 1) * 1024 + (mf & 1) * 512) = hp;                                \
    }                                                                             \
    /* prefetch NEXT step's kf0 A-quad (static W region, no hazard): its LDS */   \
    /* pipe time + latency land in the barrier-drain window */                    \
    pa0 = AF(0, 0); pa1 = AF(0, 1); pa2 = AF(0, 2); pa3 = AF(0, 3);               \
    asm volatile("s_waitcnt lgkmcnt(0)\n\ts_barrier" ::: "memory");               \
  }

  #pragma unroll 1
  for (int s2 = 0; s2 < SEQ; s2 += 2) {
    SCAN_STEP(s2,     16384, 0)      // even step: read buf1, write buf0
    SCAN_STEP(s2 + 1, 0,     16384)  // odd step:  read buf0, write buf1
  }
#undef SCAN_STEP
#undef HB
#undef AF
}

extern "C" void kernel_launch(void* const* d_in, const int* in_sizes, int n_in,
                              void* d_out, int out_size, void* d_ws, size_t ws_size,
                              hipStream_t stream) {
  (void)in_sizes; (void)n_in; (void)out_size;
  const float* X   = (const float*)d_in[0];
  const float* Wih = (const float*)d_in[1];
  const float* Whh = (const float*)d_in[2];
  const float* bih = (const float*)d_in[3];
  const float* bhh = (const float*)d_in[4];
  float* out = (float*)d_out;

  unsigned short* wihf = (unsigned short*)d_ws;              // 512 KB
  unsigned short* whhf = wihf + 262144;                      // 512 KB
  float* bsum = (float*)(whhf + 262144);                     // 2 KB
  if (ws_size < (size_t)(2 * 524288 + 2048)) return;

  prep_wfrag<<<1024, 256, 0, stream>>>(Wih, wihf);
  prep_wfrag<<<1024, 256, 0, stream>>>(Whh, whhf);
  prep_bsum<<<1, 512, 0, stream>>>(bih, bhh, bsum);

  rnn_xproj<<<2048, 512, 0, stream>>>(X, (const uint4*)wihf, bsum, out);

  hipFuncSetAttribute(reinterpret_cast<const void*>(rnn_scan),
                      hipFuncAttributeMaxDynamicSharedMemorySize, 163840);
  rnn_scan<<<4, 512, 163840, stream>>>((const uint4*)whhf, out);
}